// Round 17
// baseline (53.559 us; speedup 1.0000x reference)
//
#include <hip/hip_runtime.h>
#include <math.h>

#define PATTERNS 6
#define ITERS 50
#define LAMBDA_ 100.0f
// 1/(sqrt(2)*SIGMA), SIGMA=1.5
#define CST 0.47140452079103173f

typedef float v2f __attribute__((ext_vector_type(2)));

// xor-swizzle add within 16-lane groups (BitMode patterns; one DS inst per step)
__device__ __forceinline__ float grpsum16(float x) {
    x += __int_as_float(__builtin_amdgcn_ds_swizzle(__float_as_int(x), 0x041F)); // xor 1
    x += __int_as_float(__builtin_amdgcn_ds_swizzle(__float_as_int(x), 0x081F)); // xor 2
    x += __int_as_float(__builtin_amdgcn_ds_swizzle(__float_as_int(x), 0x101F)); // xor 4
    x += __int_as_float(__builtin_amdgcn_ds_swizzle(__float_as_int(x), 0x201F)); // xor 8
    return x;
}

#define PAIRS(X) X(0) X(1) X(2) X(3) X(4) X(5) X(6) X(7)

// Closed-form composition of K frozen-Jacobian (affine) Newton steps.
// r_{j+1} = G r_j, G = LAMBDA*rda*adj(A) (symmetric, commuting family);
// x_K = x + D*S_K*r0, S_K = sum_{j<K} G^j via binary doubling.
// Pinned-bg (clamp at 1) fallback: 1D geometric recursion for I.
template<int K>
__device__ __forceinline__ void compose_window(
    float Ua0, float Ua1, float Ua2,
    float b0a, float b1a, float rda, float Ia, float bga,
    float& I, float& bg)
{
    float a00 = Ua2 + LAMBDA_;
    float a01 = Ua1;
    float a11 = Ua0 + LAMBDA_;
    float r0I = b0a - fmaf(Ua2, I - Ia, Ua1 * (bg - bga));
    float r0B = b1a - fmaf(Ua1, I - Ia, Ua0 * (bg - bga));
    float lr = LAMBDA_ * rda;
    float G00 = lr * a11;
    float G01 = -(lr * a01);
    float G11 = lr * a00;
    float Pd00 = G00, Pd01 = G01, Pd11 = G11;
    float Sd00 = 1.0f, Sd01 = 0.0f, Sd11 = 1.0f;
    float Pa00 = 1.0f, Pa01 = 0.0f, Pa11 = 1.0f;
    float Sa00 = 0.0f, Sa01 = 0.0f, Sa11 = 0.0f;
    float T00, T01, T11;
#define SYMMUL(p,q,r_, s_,t_,u_) \
    T00 = fmaf(p, s_, q * t_); \
    T01 = fmaf(p, t_, q * u_); \
    T11 = fmaf(q, t_, r_ * u_);
#pragma unroll
    for (int j = 0; j < 6; ++j) {
        if ((K >> j) & 1) {
            SYMMUL(Pa00, Pa01, Pa11, Sd00, Sd01, Sd11)
            Sa00 += T00; Sa01 += T01; Sa11 += T11;
            SYMMUL(Pa00, Pa01, Pa11, Pd00, Pd01, Pd11)
            Pa00 = T00; Pa01 = T01; Pa11 = T11;
        }
        if ((K >> (j + 1)) != 0) {
            SYMMUL(Pd00, Pd01, Pd11, Sd00, Sd01, Sd11)
            Sd00 += T00; Sd01 += T01; Sd11 += T11;
            SYMMUL(Pd00, Pd01, Pd11, Pd00, Pd01, Pd11)
            Pd00 = T00; Pd01 = T01; Pd11 = T11;
        }
    }
#undef SYMMUL
    float w0 = fmaf(Sa00, r0I, Sa01 * r0B);
    float w1 = fmaf(Sa01, r0I, Sa11 * r0B);
    float I2  = I  + rda * fmaf(a11, w0, -(a01 * w1));
    float bg2 = bg + rda * fmaf(a00, w1, -(a01 * w0));
    float gam = rda * fmaf(a11, Ua2, -(a01 * Ua1));
    float c0 = b0a - Ua1 * (1.0f - bga);
    float c1 = b1a - Ua0 * (1.0f - bga);
    float beta = rda * fmaf(a11, c0, -(a01 * c1));
    float Iinf = Ia + beta * __builtin_amdgcn_rcpf(gam);
    float t = 1.0f - gam;
    float rho = 1.0f, tp = t;
#pragma unroll
    for (int j = 0; j < 6; ++j) {
        if ((K >> j) & 1) rho *= tp;
        if ((K >> (j + 1)) != 0) tp *= tp;
    }
    float I1d = Iinf + rho * (I - Iinf);
    bool interior = (bg2 >= 1.0f);
    I  = interior ? I2 : I1d;
    bg = interior ? bg2 : 1.0f;
    I  = fminf(fmaxf(I, 1.0f), 1000000.0f);
    bg = fminf(bg, 1000.0f);
}

// 16 lanes per job: lane `sub` owns row `sub` (16 px, register-resident).
// Halved per-lane state (g 16 + s 16 floats) vs the 8-lane mapping -> higher
// occupancy for latency hiding (the kernel is latency-bound at 3 waves/SIMD).
// Sufficient-statistics Newton (T1=sum s/mu, T2=sum s/mu^2; 4 VALU + 1 rcp/px).
// Shared-erf prologue: 4 erfs/lane + 16 bpermute broadcasts.
// Trajectory (R14/R16-proven): 3 fulls {0,1,2} + composed 22-step window +
// full refresh @25 + composed 24-step window.
__global__ __launch_bounds__(256, 4) void intensity_kernel(
    const float* __restrict__ params,
    const float* __restrict__ data,
    float* __restrict__ out,
    int njobs)
{
    const int tid = blockIdx.x * 256 + threadIdx.x;
    const int job = tid >> 4;
    const int sub = tid & 15;
    if (job >= njobs) return;
    const int spot = job / PATTERNS;

    const float x = params[spot * 5 + 0];
    const float y = params[spot * 5 + 1];
    float I = params[spot * 5 + 4] * (1.0f / PATTERNS);
    float bg = 0.0f;

#define DECLV(k) v2f g##k, s##k;
    PAIRS(DECLV)
#undef DECLV

    // this lane's 16 samples: row `sub` contiguous in memory
    {
        const float4* dp = reinterpret_cast<const float4*>(data + (size_t)job * 256 + sub * 16);
        float4 v;
        v = dp[0]; s0 = (v2f){v.x, v.y}; s1 = (v2f){v.z, v.w};
        v = dp[1]; s2 = (v2f){v.x, v.y}; s3 = (v2f){v.z, v.w};
        v = dp[2]; s4 = (v2f){v.x, v.y}; s5 = (v2f){v.z, v.w};
        v = dp[3]; s6 = (v2f){v.x, v.y}; s7 = (v2f){v.z, v.w};
    }

    // psf: g = Ey(row) * Ex(col).
    // Each lane: own-row Ey (2 erfs) + own-column Ex edge (2 erfs); 16 bpermute
    // broadcasts distribute all 16 Ex values across the 16-lane group.
    {
        const float fy = (float)sub - y;
        const float eyl = 0.5f * (erff((fy + 1.0f) * CST) - erff(fy * CST));
        const float fx = (float)sub - x;
        const float exa = 0.5f * (erff((fx + 1.0f) * CST) - erff(fx * CST));

        const int wl = threadIdx.x & 63;
        const int gb4 = (wl & 0x30) << 2;     // (group base lane) * 4

        int idx; float eA, eB;
#define MKG(k) \
        idx = gb4 + ((2 * k) << 2); \
        eA = __int_as_float(__builtin_amdgcn_ds_bpermute(idx,     __float_as_int(exa))); \
        eB = __int_as_float(__builtin_amdgcn_ds_bpermute(idx + 4, __float_as_int(exa))); \
        g##k = (v2f){eyl * eA, eyl * eB};
        MKG(0) MKG(1) MKG(2) MKG(3) MKG(4) MKG(5) MKG(6) MKG(7)
#undef MKG
    }

    // one-time sums: S_g (spsf) and S_s over all 256 pixels
    float spsf, Ss;
    {
        v2f sp = (v2f){0.0f, 0.0f};
        v2f ssum = (v2f){0.0f, 0.0f};
#define ADDG(k) sp += g##k; ssum += s##k;
        PAIRS(ADDG)
#undef ADDG
        spsf = grpsum16(sp[0] + sp[1]);
        Ss   = grpsum16(ssum[0] + ssum[1]);
    }

    // anchor state for the affine windows
    float Ua0 = 0.0f, Ua1 = 0.0f, Ua2 = 0.0f;
    float b0a = 0.0f, b1a = 0.0f, rda = 0.0f, Ia = 0.0f, bga = 0.0f;

#define BODY(k) { \
        v2f mu = g##k * I + bge; \
        v2f r; \
        r[0] = __builtin_amdgcn_rcpf(mu[0]); \
        r[1] = __builtin_amdgcn_rcpf(mu[1]); \
        v2f t = s##k * r; \
        P1 += t; \
        P2 = t * r + P2; }

#define FULL_ITER { \
        const float bge = bg + 1e-9f; \
        v2f P1 = (v2f){0.0f, 0.0f}, P2 = (v2f){0.0f, 0.0f}; \
        PAIRS(BODY) \
        float T1 = grpsum16(P1[0] + P1[1]); \
        float T2 = grpsum16(P2[0] + P2[1]); \
        float rI = __builtin_amdgcn_rcpf(I); \
        float U0 = T2; \
        float U1 = (T1 - bge * T2) * rI; \
        float U2 = fmaf(bge, fmaf(bge, T2, -(T1 + T1)), Ss) * (rI * rI); \
        float b0 = fmaf(-bge, T1, Ss) * rI - spsf; \
        float b1 = T1 - 256.0f; \
        float a00 = U2 + LAMBDA_; \
        float a01 = U1; \
        float a11 = U0 + LAMBDA_; \
        float det = fmaf(a00, a11, -(a01 * a01)); \
        float rd = __builtin_amdgcn_rcpf(det); \
        Ua0 = U0; Ua1 = U1; Ua2 = U2; \
        b0a = b0; b1a = b1; rda = rd; Ia = I; bga = bg; \
        float dI  = fmaf(a11, b0, -(a01 * b1)) * rd; \
        float dbg = fmaf(a00, b1, -(a01 * b0)) * rd; \
        I  = fminf(fmaxf(I + dI, 1.0f), 1000000.0f); \
        bg = fminf(fmaxf(bg + dbg, 1.0f), 1000.0f); }

    // iters 0-2: full (bg fast-mode transient, incl. iter-0 clip regime)
    FULL_ITER
    FULL_ITER
    FULL_ITER
    // iters 3-24: composed affine window (anchor = iter 2)
    compose_window<22>(Ua0, Ua1, Ua2, b0a, b1a, rda, Ia, bga, I, bg);
    // iter 25: full refresh
    FULL_ITER
    // iters 26-49: composed affine window (anchor = iter 25)
    compose_window<24>(Ua0, Ua1, Ua2, b0a, b1a, rda, Ia, bga, I, bg);

#undef BODY
#undef FULL_ITER

    // epilogue: CRLB + chisq. bg>=1 and g>=0 -> mu>=1 (no clip needed);
    // 1/(mu+0.01) = inv*(1-0.01*inv) to first order (err <= 1e-4 relative).
    // V1 = sum 1/mu; F11 = V1; F01 = (256 - bg*V1)/I;
    // F00 = (I*S_g - 256*bg + bg^2*V1)/I^2.
    float V1 = 0.0f, chis = 0.0f;
#define EPI(k) { \
        v2f mu = g##k * I + bg; \
        v2f inv; \
        inv[0] = __builtin_amdgcn_rcpf(mu[0]); \
        inv[1] = __builtin_amdgcn_rcpf(mu[1]); \
        v2f d  = s##k - mu; \
        v2f ic; \
        ic[0] = fmaf(-0.01f * inv[0], inv[0], inv[0]); \
        ic[1] = fmaf(-0.01f * inv[1], inv[1], inv[1]); \
        V1 += inv[0] + inv[1]; \
        chis += d[0] * d[0] * ic[0] + d[1] * d[1] * ic[1]; }
    PAIRS(EPI)
#undef EPI
    {
        float t0 = __int_as_float(__builtin_amdgcn_ds_swizzle(__float_as_int(V1), 0x041F));
        float t1 = __int_as_float(__builtin_amdgcn_ds_swizzle(__float_as_int(chis), 0x041F));
        V1 += t0; chis += t1;
        t0 = __int_as_float(__builtin_amdgcn_ds_swizzle(__float_as_int(V1), 0x081F));
        t1 = __int_as_float(__builtin_amdgcn_ds_swizzle(__float_as_int(chis), 0x081F));
        V1 += t0; chis += t1;
        t0 = __int_as_float(__builtin_amdgcn_ds_swizzle(__float_as_int(V1), 0x101F));
        t1 = __int_as_float(__builtin_amdgcn_ds_swizzle(__float_as_int(chis), 0x101F));
        V1 += t0; chis += t1;
        t0 = __int_as_float(__builtin_amdgcn_ds_swizzle(__float_as_int(V1), 0x201F));
        t1 = __int_as_float(__builtin_amdgcn_ds_swizzle(__float_as_int(chis), 0x201F));
        V1 += t0; chis += t1;
    }

    if (sub == 0) {
        float rI = __builtin_amdgcn_rcpf(I);
        float F11 = V1;
        float F01 = fmaf(-bg, V1, 256.0f) * rI;
        float F00 = (fmaf(bg * bg, V1, I * spsf) - 256.0f * bg) * (rI * rI);
        float detF = fmaf(F00, F11, -(F01 * F01));
        float rdF = __builtin_amdgcn_rcpf(detF);
        float* o = out + (size_t)job * 5;
        o[0] = I;
        o[1] = bg;
        o[2] = sqrtf(F11 * rdF);
        o[3] = sqrtf(F00 * rdF);
        o[4] = chis;
    }
}

extern "C" void kernel_launch(void* const* d_in, const int* in_sizes, int n_in,
                              void* d_out, int out_size, void* d_ws, size_t ws_size,
                              hipStream_t stream) {
    const float* params = (const float*)d_in[0];
    const float* data   = (const float*)d_in[1];
    float* out = (float*)d_out;
    int nspots = in_sizes[0] / 5;
    int njobs = nspots * PATTERNS;
    long long nthreads = (long long)njobs * 16;
    int blocks = (int)((nthreads + 255) / 256);
    intensity_kernel<<<dim3(blocks), dim3(256), 0, stream>>>(params, data, out, njobs);
}

// Round 18
// 44.054 us; speedup vs baseline: 1.2158x; 1.2158x over previous
//
#include <hip/hip_runtime.h>
#include <math.h>

#define PATTERNS 6
#define ITERS 50
#define LAMBDA_ 100.0f
// 1/(sqrt(2)*SIGMA), SIGMA=1.5
#define CST 0.47140452079103173f

typedef float v2f __attribute__((ext_vector_type(2)));

// xor-swizzle add within 8-lane groups (proven; one DS inst per step)
__device__ __forceinline__ float grpsum8(float x) {
    x += __int_as_float(__builtin_amdgcn_ds_swizzle(__float_as_int(x), 0x041F)); // xor 1
    x += __int_as_float(__builtin_amdgcn_ds_swizzle(__float_as_int(x), 0x081F)); // xor 2
    x += __int_as_float(__builtin_amdgcn_ds_swizzle(__float_as_int(x), 0x101F)); // xor 4
    return x;
}

#define COLS(X) X(0) X(1) X(2) X(3) X(4) X(5) X(6) X(7)

// Closed-form composition of K frozen-Jacobian (affine) Newton steps (proven R16).
template<int K>
__device__ __forceinline__ void compose_window(
    float Ua0, float Ua1, float Ua2,
    float b0a, float b1a, float rda, float Ia, float bga,
    float& I, float& bg)
{
    float a00 = Ua2 + LAMBDA_;
    float a01 = Ua1;
    float a11 = Ua0 + LAMBDA_;
    float r0I = b0a - fmaf(Ua2, I - Ia, Ua1 * (bg - bga));
    float r0B = b1a - fmaf(Ua1, I - Ia, Ua0 * (bg - bga));
    float lr = LAMBDA_ * rda;
    float G00 = lr * a11;
    float G01 = -(lr * a01);
    float G11 = lr * a00;
    float Pd00 = G00, Pd01 = G01, Pd11 = G11;
    float Sd00 = 1.0f, Sd01 = 0.0f, Sd11 = 1.0f;
    float Pa00 = 1.0f, Pa01 = 0.0f, Pa11 = 1.0f;
    float Sa00 = 0.0f, Sa01 = 0.0f, Sa11 = 0.0f;
    float T00, T01, T11;
#define SYMMUL(p,q,r_, s_,t_,u_) \
    T00 = fmaf(p, s_, q * t_); \
    T01 = fmaf(p, t_, q * u_); \
    T11 = fmaf(q, t_, r_ * u_);
#pragma unroll
    for (int j = 0; j < 6; ++j) {
        if ((K >> j) & 1) {
            SYMMUL(Pa00, Pa01, Pa11, Sd00, Sd01, Sd11)
            Sa00 += T00; Sa01 += T01; Sa11 += T11;
            SYMMUL(Pa00, Pa01, Pa11, Pd00, Pd01, Pd11)
            Pa00 = T00; Pa01 = T01; Pa11 = T11;
        }
        if ((K >> (j + 1)) != 0) {
            SYMMUL(Pd00, Pd01, Pd11, Sd00, Sd01, Sd11)
            Sd00 += T00; Sd01 += T01; Sd11 += T11;
            SYMMUL(Pd00, Pd01, Pd11, Pd00, Pd01, Pd11)
            Pd00 = T00; Pd01 = T01; Pd11 = T11;
        }
    }
#undef SYMMUL
    float w0 = fmaf(Sa00, r0I, Sa01 * r0B);
    float w1 = fmaf(Sa01, r0I, Sa11 * r0B);
    float I2  = I  + rda * fmaf(a11, w0, -(a01 * w1));
    float bg2 = bg + rda * fmaf(a00, w1, -(a01 * w0));
    float gam = rda * fmaf(a11, Ua2, -(a01 * Ua1));
    float c0 = b0a - Ua1 * (1.0f - bga);
    float c1 = b1a - Ua0 * (1.0f - bga);
    float beta = rda * fmaf(a11, c0, -(a01 * c1));
    float Iinf = Ia + beta * __builtin_amdgcn_rcpf(gam);
    float t = 1.0f - gam;
    float rho = 1.0f, tp = t;
#pragma unroll
    for (int j = 0; j < 6; ++j) {
        if ((K >> j) & 1) rho *= tp;
        if ((K >> (j + 1)) != 0) tp *= tp;
    }
    float I1d = Iinf + rho * (I - Iinf);
    bool interior = (bg2 >= 1.0f);
    I  = interior ? I2 : I1d;
    bg = interior ? bg2 : 1.0f;
    I  = fminf(fmaxf(I, 1.0f), 1000000.0f);
    bg = fminf(bg, 1000.0f);
}

// 8 lanes per job (R16 mapping), register-diet edition:
//  - samples s in LDS (XOR bank-swizzle, 32KB/block -> 5 blocks/CU) [-32 VGPR]
//  - g factored as eyl_row * ex_col: store 8 v2f ex + 2 eyl      [-14 VGPR]
// Sufficient-statistics Newton; 3 fulls {0,1,2} + compose<22> + refresh@25 +
// compose<24> (R16-proven trajectory).
__global__ __launch_bounds__(256, 5) void intensity_kernel(
    const float* __restrict__ params,
    const float* __restrict__ data,
    float* __restrict__ out,
    int njobs)
{
    __shared__ float slds[256 * 32];   // 32 KB

    const int t = threadIdx.x;
    const int tid = blockIdx.x * 256 + t;
    const int job = tid >> 3;
    const int sub = tid & 7;
    if (job >= njobs) return;
    const int spot = job / PATTERNS;

    // byte base with XOR swizzle: addr(k) = laneB ^ (k<<3), k = pair index 0..15
    const int laneB = (t << 7) ^ ((t & 15) << 3);
#define SADDR(k) (*(v2f*)((char*)slds + (laneB ^ ((k) << 3))))

    const float x = params[spot * 5 + 0];
    const float y = params[spot * 5 + 1];
    float I = params[spot * 5 + 4] * (1.0f / PATTERNS);
    float bg = 0.0f;

    // load this lane's 32 samples (rows 2*sub, 2*sub+1), accumulate Ss, park in LDS
    float Ss;
    {
        const float4* dp = reinterpret_cast<const float4*>(data + (size_t)job * 256 + sub * 32);
        float ssum = 0.0f;
#pragma unroll
        for (int q = 0; q < 8; ++q) {
            float4 v = dp[q];
            ssum += (v.x + v.y) + (v.z + v.w);
            SADDR(2 * q)     = (v2f){v.x, v.y};
            SADDR(2 * q + 1) = (v2f){v.z, v.w};
        }
        Ss = grpsum8(ssum);
    }

    // psf factors: eyl0/eyl1 (rows 2*sub, 2*sub+1) + shared column edges ex0..ex7
    v2f ex0, ex1, ex2, ex3, ex4, ex5, ex6, ex7;
    float eyl0, eyl1, spsf;
    {
        const float r0f = (float)(2 * sub);
        const float ey_a = erff((r0f - y) * CST);
        const float ey_b = erff((r0f + 1.0f - y) * CST);
        const float ey_c = erff((r0f + 2.0f - y) * CST);
        eyl0 = 0.5f * (ey_b - ey_a);
        eyl1 = 0.5f * (ey_c - ey_b);

        const float c0 = (float)(2 * sub);
        const float ea = erff((c0 - x) * CST);
        const float eb = erff((c0 + 1.0f - x) * CST);
        const float ec = erff((c0 + 2.0f - x) * CST);
        const float exa = 0.5f * (eb - ea);   // ex for col 2*sub
        const float exb = 0.5f * (ec - eb);   // ex for col 2*sub+1

        const int wl = t & 63;
        const int gb4 = (wl & 0x38) << 2;     // (group base lane) * 4

        int idx; float eA, eB;
#define MKEX(k) \
        idx = gb4 + ((k) << 2); \
        eA = __int_as_float(__builtin_amdgcn_ds_bpermute(idx, __float_as_int(exa))); \
        eB = __int_as_float(__builtin_amdgcn_ds_bpermute(idx, __float_as_int(exb))); \
        ex##k = (v2f){eA, eB};
        COLS(MKEX)
#undef MKEX
        // spsf = (sum of ex over 16 cols) * (group-sum of eyl0+eyl1)
        v2f exs = ex0 + ex1 + ex2 + ex3 + ex4 + ex5 + ex6 + ex7;
        spsf = (exs[0] + exs[1]) * grpsum8(eyl0 + eyl1);
    }

    // anchor state for the affine windows
    float Ua0 = 0.0f, Ua1 = 0.0f, Ua2 = 0.0f;
    float b0a = 0.0f, b1a = 0.0f, rda = 0.0f, Ia = 0.0f, bga = 0.0f;

#define BODYA(k) { \
        v2f s = SADDR(k); \
        v2f mu = ex##k * IeyA + bge; \
        v2f r; \
        r[0] = __builtin_amdgcn_rcpf(mu[0]); \
        r[1] = __builtin_amdgcn_rcpf(mu[1]); \
        v2f tt = s * r; \
        P1 += tt; \
        P2 = tt * r + P2; }
#define BODYB(k) { \
        v2f s = SADDR(8 + k); \
        v2f mu = ex##k * IeyB + bge; \
        v2f r; \
        r[0] = __builtin_amdgcn_rcpf(mu[0]); \
        r[1] = __builtin_amdgcn_rcpf(mu[1]); \
        v2f tt = s * r; \
        P1 += tt; \
        P2 = tt * r + P2; }

#define FULL_ITER { \
        const float bge = bg + 1e-9f; \
        const float IeyA = I * eyl0; \
        const float IeyB = I * eyl1; \
        v2f P1 = (v2f){0.0f, 0.0f}, P2 = (v2f){0.0f, 0.0f}; \
        COLS(BODYA) \
        COLS(BODYB) \
        float T1 = grpsum8(P1[0] + P1[1]); \
        float T2 = grpsum8(P2[0] + P2[1]); \
        float rI = __builtin_amdgcn_rcpf(I); \
        float U0 = T2; \
        float U1 = (T1 - bge * T2) * rI; \
        float U2 = fmaf(bge, fmaf(bge, T2, -(T1 + T1)), Ss) * (rI * rI); \
        float b0 = fmaf(-bge, T1, Ss) * rI - spsf; \
        float b1 = T1 - 256.0f; \
        float a00 = U2 + LAMBDA_; \
        float a01 = U1; \
        float a11 = U0 + LAMBDA_; \
        float det = fmaf(a00, a11, -(a01 * a01)); \
        float rd = __builtin_amdgcn_rcpf(det); \
        Ua0 = U0; Ua1 = U1; Ua2 = U2; \
        b0a = b0; b1a = b1; rda = rd; Ia = I; bga = bg; \
        float dI  = fmaf(a11, b0, -(a01 * b1)) * rd; \
        float dbg = fmaf(a00, b1, -(a01 * b0)) * rd; \
        I  = fminf(fmaxf(I + dI, 1.0f), 1000000.0f); \
        bg = fminf(fmaxf(bg + dbg, 1.0f), 1000.0f); }

    // iters 0-2: full (bg fast-mode transient, incl. iter-0 clip regime)
    FULL_ITER
    FULL_ITER
    FULL_ITER
    // iters 3-24: composed affine window (anchor = iter 2)
    compose_window<22>(Ua0, Ua1, Ua2, b0a, b1a, rda, Ia, bga, I, bg);
    // iter 25: full refresh
    FULL_ITER
    // iters 26-49: composed affine window (anchor = iter 25)
    compose_window<24>(Ua0, Ua1, Ua2, b0a, b1a, rda, Ia, bga, I, bg);

#undef BODYA
#undef BODYB
#undef FULL_ITER

    // epilogue: CRLB + chisq (mu>=1 after clamps; 1/(mu+0.01) ~ inv*(1-0.01*inv))
    float V1 = 0.0f, chis = 0.0f;
    {
        const float IeyA = I * eyl0;
        const float IeyB = I * eyl1;
#define EPIA(k) { \
        v2f s = SADDR(k); \
        v2f mu = ex##k * IeyA + bg; \
        v2f inv; \
        inv[0] = __builtin_amdgcn_rcpf(mu[0]); \
        inv[1] = __builtin_amdgcn_rcpf(mu[1]); \
        v2f d  = s - mu; \
        v2f ic; \
        ic[0] = fmaf(-0.01f * inv[0], inv[0], inv[0]); \
        ic[1] = fmaf(-0.01f * inv[1], inv[1], inv[1]); \
        V1 += inv[0] + inv[1]; \
        chis += d[0] * d[0] * ic[0] + d[1] * d[1] * ic[1]; }
#define EPIB(k) { \
        v2f s = SADDR(8 + k); \
        v2f mu = ex##k * IeyB + bg; \
        v2f inv; \
        inv[0] = __builtin_amdgcn_rcpf(mu[0]); \
        inv[1] = __builtin_amdgcn_rcpf(mu[1]); \
        v2f d  = s - mu; \
        v2f ic; \
        ic[0] = fmaf(-0.01f * inv[0], inv[0], inv[0]); \
        ic[1] = fmaf(-0.01f * inv[1], inv[1], inv[1]); \
        V1 += inv[0] + inv[1]; \
        chis += d[0] * d[0] * ic[0] + d[1] * d[1] * ic[1]; }
        COLS(EPIA)
        COLS(EPIB)
#undef EPIA
#undef EPIB
    }
    {
        float t0 = __int_as_float(__builtin_amdgcn_ds_swizzle(__float_as_int(V1), 0x041F));
        float t1 = __int_as_float(__builtin_amdgcn_ds_swizzle(__float_as_int(chis), 0x041F));
        V1 += t0; chis += t1;
        t0 = __int_as_float(__builtin_amdgcn_ds_swizzle(__float_as_int(V1), 0x081F));
        t1 = __int_as_float(__builtin_amdgcn_ds_swizzle(__float_as_int(chis), 0x081F));
        V1 += t0; chis += t1;
        t0 = __int_as_float(__builtin_amdgcn_ds_swizzle(__float_as_int(V1), 0x101F));
        t1 = __int_as_float(__builtin_amdgcn_ds_swizzle(__float_as_int(chis), 0x101F));
        V1 += t0; chis += t1;
    }

    if (sub == 0) {
        float rI = __builtin_amdgcn_rcpf(I);
        float F11 = V1;
        float F01 = fmaf(-bg, V1, 256.0f) * rI;
        float F00 = (fmaf(bg * bg, V1, I * spsf) - 256.0f * bg) * (rI * rI);
        float detF = fmaf(F00, F11, -(F01 * F01));
        float rdF = __builtin_amdgcn_rcpf(detF);
        float* o = out + (size_t)job * 5;
        o[0] = I;
        o[1] = bg;
        o[2] = sqrtf(F11 * rdF);
        o[3] = sqrtf(F00 * rdF);
        o[4] = chis;
    }
#undef SADDR
}

extern "C" void kernel_launch(void* const* d_in, const int* in_sizes, int n_in,
                              void* d_out, int out_size, void* d_ws, size_t ws_size,
                              hipStream_t stream) {
    const float* params = (const float*)d_in[0];
    const float* data   = (const float*)d_in[1];
    float* out = (float*)d_out;
    int nspots = in_sizes[0] / 5;
    int njobs = nspots * PATTERNS;
    long long nthreads = (long long)njobs * 8;
    int blocks = (int)((nthreads + 255) / 256);
    intensity_kernel<<<dim3(blocks), dim3(256), 0, stream>>>(params, data, out, njobs);
}

// Round 19
// 43.233 us; speedup vs baseline: 1.2389x; 1.0190x over previous
//
#include <hip/hip_runtime.h>
#include <math.h>

#define PATTERNS 6
#define ITERS 50
#define LAMBDA_ 100.0f
// 1/(sqrt(2)*SIGMA), SIGMA=1.5
#define CST 0.47140452079103173f

typedef float v2f __attribute__((ext_vector_type(2)));

// xor-swizzle add within 8-lane groups (proven; one DS inst per step)
__device__ __forceinline__ float grpsum8(float x) {
    x += __int_as_float(__builtin_amdgcn_ds_swizzle(__float_as_int(x), 0x041F)); // xor 1
    x += __int_as_float(__builtin_amdgcn_ds_swizzle(__float_as_int(x), 0x081F)); // xor 2
    x += __int_as_float(__builtin_amdgcn_ds_swizzle(__float_as_int(x), 0x101F)); // xor 4
    return x;
}

#define PAIRS(X) X(0) X(1) X(2) X(3) X(4) X(5) X(6) X(7) \
                 X(8) X(9) X(10) X(11) X(12) X(13) X(14) X(15)

// Closed-form composition of K frozen-Jacobian (affine) Newton steps.
// r_{j+1} = G r_j, G = LAMBDA*rda*adj(A) (symmetric, commuting family);
// x_K = x + D*S_K*r0, S_K = sum_{j<K} G^j via binary doubling.
// Pinned-bg (clamp at 1) fallback: 1D geometric recursion for I.
template<int K>
__device__ __forceinline__ void compose_window(
    float Ua0, float Ua1, float Ua2,
    float b0a, float b1a, float rda, float Ia, float bga,
    float& I, float& bg)
{
    float a00 = Ua2 + LAMBDA_;
    float a01 = Ua1;
    float a11 = Ua0 + LAMBDA_;
    // residual of the linear model at current x
    float r0I = b0a - fmaf(Ua2, I - Ia, Ua1 * (bg - bga));
    float r0B = b1a - fmaf(Ua1, I - Ia, Ua0 * (bg - bga));
    // G = lambda * D (symmetric: G00, G01, G11)
    float lr = LAMBDA_ * rda;
    float G00 = lr * a11;
    float G01 = -(lr * a01);
    float G11 = lr * a00;
    // doubling state: (Pd,Sd) = (G^(2^j), S_(2^j)); accumulator (Pa,Sa)
    float Pd00 = G00, Pd01 = G01, Pd11 = G11;
    float Sd00 = 1.0f, Sd01 = 0.0f, Sd11 = 1.0f;
    float Pa00 = 1.0f, Pa01 = 0.0f, Pa11 = 1.0f;
    float Sa00 = 0.0f, Sa01 = 0.0f, Sa11 = 0.0f;
    float T00, T01, T11;
#define SYMMUL(p,q,r_, s_,t_,u_) \
    T00 = fmaf(p, s_, q * t_); \
    T01 = fmaf(p, t_, q * u_); \
    T11 = fmaf(q, t_, r_ * u_);
#pragma unroll
    for (int j = 0; j < 6; ++j) {
        if ((K >> j) & 1) {
            SYMMUL(Pa00, Pa01, Pa11, Sd00, Sd01, Sd11)
            Sa00 += T00; Sa01 += T01; Sa11 += T11;
            SYMMUL(Pa00, Pa01, Pa11, Pd00, Pd01, Pd11)
            Pa00 = T00; Pa01 = T01; Pa11 = T11;
        }
        if ((K >> (j + 1)) != 0) {
            SYMMUL(Pd00, Pd01, Pd11, Sd00, Sd01, Sd11)
            Sd00 += T00; Sd01 += T01; Sd11 += T11;
            SYMMUL(Pd00, Pd01, Pd11, Pd00, Pd01, Pd11)
            Pd00 = T00; Pd01 = T01; Pd11 = T11;
        }
    }
#undef SYMMUL
    // w = Sa * r0 ; dx = D * w
    float w0 = fmaf(Sa00, r0I, Sa01 * r0B);
    float w1 = fmaf(Sa01, r0I, Sa11 * r0B);
    float I2  = I  + rda * fmaf(a11, w0, -(a01 * w1));
    float bg2 = bg + rda * fmaf(a00, w1, -(a01 * w0));
    // pinned-bg fallback: bg clamped at 1; dI_j = beta - gam*(I_j - Ia)
    float gam = rda * fmaf(a11, Ua2, -(a01 * Ua1));
    float c0 = b0a - Ua1 * (1.0f - bga);
    float c1 = b1a - Ua0 * (1.0f - bga);
    float beta = rda * fmaf(a11, c0, -(a01 * c1));
    float Iinf = Ia + beta * __builtin_amdgcn_rcpf(gam);
    float t = 1.0f - gam;
    float rho = 1.0f, tp = t;
#pragma unroll
    for (int j = 0; j < 6; ++j) {
        if ((K >> j) & 1) rho *= tp;
        if ((K >> (j + 1)) != 0) tp *= tp;
    }
    float I1d = Iinf + rho * (I - Iinf);
    bool interior = (bg2 >= 1.0f);
    I  = interior ? I2 : I1d;
    bg = interior ? bg2 : 1.0f;
    I  = fminf(fmaxf(I, 1.0f), 1000000.0f);
    bg = fminf(bg, 1000.0f);
}

// 8 lanes per job: lane `sub` owns rows 2*sub, 2*sub+1 (32 px, register-resident).
// Sufficient-statistics Newton (T1=sum s/mu, T2=sum s/mu^2; 4 VALU + 1 rcp per px).
// Shared-erf prologue via ds_bpermute (erf/lane: 20 -> 6).
// Trajectory (R14-proven schedule, composed in closed form): 3 fulls {0,1,2} +
// composed 22-step window (iters 3-24) + full refresh @25 + composed 24-step
// window (iters 26-49).
__global__ __launch_bounds__(256, 3) void intensity_kernel(
    const float* __restrict__ params,
    const float* __restrict__ data,
    float* __restrict__ out,
    int njobs)
{
    const int tid = blockIdx.x * 256 + threadIdx.x;
    const int job = tid >> 3;
    const int sub = tid & 7;
    if (job >= njobs) return;
    const int spot = job / PATTERNS;

    const float x = params[spot * 5 + 0];
    const float y = params[spot * 5 + 1];
    float I = params[spot * 5 + 4] * (1.0f / PATTERNS);
    float bg = 0.0f;

#define DECLV(k) v2f g##k, s##k;
    PAIRS(DECLV)
#undef DECLV

    // this lane's 32 samples: rows 2*sub, 2*sub+1 contiguous in memory
    {
        const float4* dp = reinterpret_cast<const float4*>(data + (size_t)job * 256 + sub * 32);
        float4 v;
        v = dp[0]; s0  = (v2f){v.x, v.y}; s1  = (v2f){v.z, v.w};
        v = dp[1]; s2  = (v2f){v.x, v.y}; s3  = (v2f){v.z, v.w};
        v = dp[2]; s4  = (v2f){v.x, v.y}; s5  = (v2f){v.z, v.w};
        v = dp[3]; s6  = (v2f){v.x, v.y}; s7  = (v2f){v.z, v.w};
        v = dp[4]; s8  = (v2f){v.x, v.y}; s9  = (v2f){v.z, v.w};
        v = dp[5]; s10 = (v2f){v.x, v.y}; s11 = (v2f){v.z, v.w};
        v = dp[6]; s12 = (v2f){v.x, v.y}; s13 = (v2f){v.z, v.w};
        v = dp[7]; s14 = (v2f){v.x, v.y}; s15 = (v2f){v.z, v.w};
    }

    // psf: g = Ey(row) * Ex(col); shared-erf via ds_bpermute across the 8-lane group
    {
        const float r0f = (float)(2 * sub);
        const float ey_a = erff((r0f - y) * CST);
        const float ey_b = erff((r0f + 1.0f - y) * CST);
        const float ey_c = erff((r0f + 2.0f - y) * CST);
        const float eyl0 = 0.5f * (ey_b - ey_a);
        const float eyl1 = 0.5f * (ey_c - ey_b);

        const float c0 = (float)(2 * sub);
        const float ea = erff((c0 - x) * CST);
        const float eb = erff((c0 + 1.0f - x) * CST);
        const float ec = erff((c0 + 2.0f - x) * CST);
        const float exa = 0.5f * (eb - ea);   // ex for col 2*sub
        const float exb = 0.5f * (ec - eb);   // ex for col 2*sub+1

        const int wl = threadIdx.x & 63;
        const int gb4 = (wl & 0x38) << 2;     // (group base lane) * 4

        {
            int idx; float eA, eB;
#define MKG2(k, lo, hi) \
            idx = gb4 + (k << 2); \
            eA = __int_as_float(__builtin_amdgcn_ds_bpermute(idx, __float_as_int(exa))); \
            eB = __int_as_float(__builtin_amdgcn_ds_bpermute(idx, __float_as_int(exb))); \
            lo = (v2f){eyl0 * eA, eyl0 * eB}; \
            hi = (v2f){eyl1 * eA, eyl1 * eB};
            MKG2(0, g0, g8)
            MKG2(1, g1, g9)
            MKG2(2, g2, g10)
            MKG2(3, g3, g11)
            MKG2(4, g4, g12)
            MKG2(5, g5, g13)
            MKG2(6, g6, g14)
            MKG2(7, g7, g15)
#undef MKG2
        }
    }

    // one-time sums: S_g (spsf) and S_s over all 256 pixels
    float spsf, Ss;
    {
        v2f sp = (v2f){0.0f, 0.0f};
        v2f ssum = (v2f){0.0f, 0.0f};
#define ADDG(k) sp += g##k; ssum += s##k;
        PAIRS(ADDG)
#undef ADDG
        spsf = grpsum8(sp[0] + sp[1]);
        Ss   = grpsum8(ssum[0] + ssum[1]);
    }

    // anchor state for the affine windows
    float Ua0 = 0.0f, Ua1 = 0.0f, Ua2 = 0.0f;
    float b0a = 0.0f, b1a = 0.0f, rda = 0.0f, Ia = 0.0f, bga = 0.0f;

#define BODY(k) { \
        v2f mu = g##k * I + bge; \
        v2f r; \
        r[0] = __builtin_amdgcn_rcpf(mu[0]); \
        r[1] = __builtin_amdgcn_rcpf(mu[1]); \
        v2f t = s##k * r; \
        P1 += t; \
        P2 = t * r + P2; }

#define FULL_ITER { \
        const float bge = bg + 1e-9f; \
        v2f P1 = (v2f){0.0f, 0.0f}, P2 = (v2f){0.0f, 0.0f}; \
        PAIRS(BODY) \
        float T1 = grpsum8(P1[0] + P1[1]); \
        float T2 = grpsum8(P2[0] + P2[1]); \
        float rI = __builtin_amdgcn_rcpf(I); \
        float U0 = T2; \
        float U1 = (T1 - bge * T2) * rI; \
        float U2 = fmaf(bge, fmaf(bge, T2, -(T1 + T1)), Ss) * (rI * rI); \
        float b0 = fmaf(-bge, T1, Ss) * rI - spsf; \
        float b1 = T1 - 256.0f; \
        float a00 = U2 + LAMBDA_; \
        float a01 = U1; \
        float a11 = U0 + LAMBDA_; \
        float det = fmaf(a00, a11, -(a01 * a01)); \
        float rd = __builtin_amdgcn_rcpf(det); \
        Ua0 = U0; Ua1 = U1; Ua2 = U2; \
        b0a = b0; b1a = b1; rda = rd; Ia = I; bga = bg; \
        float dI  = fmaf(a11, b0, -(a01 * b1)) * rd; \
        float dbg = fmaf(a00, b1, -(a01 * b0)) * rd; \
        I  = fminf(fmaxf(I + dI, 1.0f), 1000000.0f); \
        bg = fminf(fmaxf(bg + dbg, 1.0f), 1000.0f); }

    // iters 0-2: full (bg fast-mode transient, incl. iter-0 clip regime)
    FULL_ITER
    FULL_ITER
    FULL_ITER
    // iters 3-24: composed affine window (anchor = iter 2)
    compose_window<22>(Ua0, Ua1, Ua2, b0a, b1a, rda, Ia, bga, I, bg);
    // iter 25: full refresh
    FULL_ITER
    // iters 26-49: composed affine window (anchor = iter 25)
    compose_window<24>(Ua0, Ua1, Ua2, b0a, b1a, rda, Ia, bga, I, bg);

#undef BODY
#undef FULL_ITER

    // epilogue: CRLB + chisq. bg>=1 and g>=0 -> mu>=1 (no clip needed);
    // 1/(mu+0.01) = inv*(1-0.01*inv) to first order (err <= 1e-4 relative).
    // V1 = sum 1/mu; F11 = V1; F01 = (256 - bg*V1)/I;
    // F00 = (I*S_g - 256*bg + bg^2*V1)/I^2.
    float V1 = 0.0f, chis = 0.0f;
#define EPI(k) { \
        v2f mu = g##k * I + bg; \
        v2f inv; \
        inv[0] = __builtin_amdgcn_rcpf(mu[0]); \
        inv[1] = __builtin_amdgcn_rcpf(mu[1]); \
        v2f d  = s##k - mu; \
        v2f ic; \
        ic[0] = fmaf(-0.01f * inv[0], inv[0], inv[0]); \
        ic[1] = fmaf(-0.01f * inv[1], inv[1], inv[1]); \
        V1 += inv[0] + inv[1]; \
        chis += d[0] * d[0] * ic[0] + d[1] * d[1] * ic[1]; }
    PAIRS(EPI)
#undef EPI
    {
        float t0 = __int_as_float(__builtin_amdgcn_ds_swizzle(__float_as_int(V1), 0x041F));
        float t1 = __int_as_float(__builtin_amdgcn_ds_swizzle(__float_as_int(chis), 0x041F));
        V1 += t0; chis += t1;
        t0 = __int_as_float(__builtin_amdgcn_ds_swizzle(__float_as_int(V1), 0x081F));
        t1 = __int_as_float(__builtin_amdgcn_ds_swizzle(__float_as_int(chis), 0x081F));
        V1 += t0; chis += t1;
        t0 = __int_as_float(__builtin_amdgcn_ds_swizzle(__float_as_int(V1), 0x101F));
        t1 = __int_as_float(__builtin_amdgcn_ds_swizzle(__float_as_int(chis), 0x101F));
        V1 += t0; chis += t1;
    }

    if (sub == 0) {
        float rI = __builtin_amdgcn_rcpf(I);
        float F11 = V1;
        float F01 = fmaf(-bg, V1, 256.0f) * rI;
        float F00 = (fmaf(bg * bg, V1, I * spsf) - 256.0f * bg) * (rI * rI);
        float detF = fmaf(F00, F11, -(F01 * F01));
        float rdF = __builtin_amdgcn_rcpf(detF);
        float* o = out + (size_t)job * 5;
        o[0] = I;
        o[1] = bg;
        o[2] = sqrtf(F11 * rdF);
        o[3] = sqrtf(F00 * rdF);
        o[4] = chis;
    }
}

extern "C" void kernel_launch(void* const* d_in, const int* in_sizes, int n_in,
                              void* d_out, int out_size, void* d_ws, size_t ws_size,
                              hipStream_t stream) {
    const float* params = (const float*)d_in[0];
    const float* data   = (const float*)d_in[1];
    float* out = (float*)d_out;
    int nspots = in_sizes[0] / 5;
    int njobs = nspots * PATTERNS;
    long long nthreads = (long long)njobs * 8;
    int blocks = (int)((nthreads + 255) / 256);
    intensity_kernel<<<dim3(blocks), dim3(256), 0, stream>>>(params, data, out, njobs);
}